// Round 15
// baseline (82.794 us; speedup 1.0000x reference)
//
#include <hip/hip_runtime.h>
#include <hip/hip_fp16.h>

// TripletLoss: N=8192, D=512, T=65536
//   loss = mean_t softplus(||x_i - x_j||^2 - ||x_i - x_k||^2)
//
// Round 15: r14 + NSLICE 32 -> 64 (8B/row/slice, 64 KiB LDS) so kernel B
// runs 2 blocks/CU (2048 thr/CU = HW cap, 32 waves/CU). r13/r14 proved B's
// loop is latency-hidden and B is single-shot-latency-bound at 1 block/CU;
// co-resident blocks now hide each other's staging/barrier latency.
//   A: fp32 -> fp8 e4m3, slice-major; each thread converts one 64B line of
//      x into TWO adjacent slices (coalesced both sides); zeroes slots+ctr.
//   B: 512 blocks (64 slices x 8 groups), stage 64 KiB slice in LDS (uint4),
//      2-stage pipelined loop, 3 random ds_read_b64/triplet, packed fma,
//      zp[s][t] fp16 coalesced.
//   C: 64 blocks combine 64 slices + softplus + slot reduce (1 add/slot).
// Fallback tiers: ws < 12.01 MB -> r7 path (proven 30.2); < 4.07 MB -> fp32.

typedef float floatx2 __attribute__((ext_vector_type(2)));

#define NTRIP  65536
#define DIM    512
#define NROWS  8192
#define NSLICE 64                  // 8 B of fp8 per row per slice
#define GGRP   8                   // triplet groups
#define TRIP_PER_G (NTRIP / GGRP)  // 8192
#define BT     1024                // kernel B block size (16 waves)
#define NIT    (TRIP_PER_G / BT)   // 8
#define NSLOT  64
#define SLOT_STRIDE 16             // floats; 64 B apart

#define XQS_BYTES ((size_t)NSLICE * NROWS * 8)          // 4 MiB (uint2 each)
#define ZP_BYTES  ((size_t)NSLICE * NTRIP * 2)          // 8 MiB (fp16)
#define NEED_NEW  (XQS_BYTES + ZP_BYTES + NSLOT * SLOT_STRIDE * 4 + 64)
#define XQ_BYTES  ((size_t)NROWS * DIM)
#define R7_NBLK   2048
#define NEED_R7   (XQ_BYTES + (size_t)R7_NBLK * 4)

__device__ __forceinline__ float softplus_stable(float z) {
    return fmaxf(z, 0.f) + log1pf(expf(-fabsf(z)));
}

__device__ __forceinline__ unsigned int enc4(float a, float b, float c, float d) {
    unsigned int w = __builtin_amdgcn_cvt_pk_fp8_f32(a, b, 0, false);
    w = __builtin_amdgcn_cvt_pk_fp8_f32(c, d, w, true);
    return w;
}

__device__ __forceinline__ void decode8v(uint2 v, floatx2* f) {
    f[0] = __builtin_amdgcn_cvt_pk_f32_fp8(v.x, false);
    f[1] = __builtin_amdgcn_cvt_pk_f32_fp8(v.x, true);
    f[2] = __builtin_amdgcn_cvt_pk_f32_fp8(v.y, false);
    f[3] = __builtin_amdgcn_cvt_pk_f32_fp8(v.y, true);
}

__device__ __forceinline__ void decode4(unsigned int w, float* f) {
    floatx2 p0 = __builtin_amdgcn_cvt_pk_f32_fp8(w, false);
    floatx2 p1 = __builtin_amdgcn_cvt_pk_f32_fp8(w, true);
    f[0] = p0.x; f[1] = p0.y; f[2] = p1.x; f[3] = p1.y;
}

__device__ __forceinline__ void decode16(uint4 v, float* f) {
    decode4(v.x, f);     decode4(v.y, f + 4);
    decode4(v.z, f + 8); decode4(v.w, f + 12);
}

// ====================== NEW PATH (LDS slice, 2 blocks/CU) ==================

// A: thread idx -> (slice-pair s2, row r). Reads 64B line x[r][s2*16..+15],
// writes slice 2*s2 (elems 0..7) and 2*s2+1 (elems 8..15), both coalesced.
__global__ __launch_bounds__(256) void convert_slice_kernel(
    const float4* __restrict__ x, uint2* __restrict__ xq_s,
    float* __restrict__ slots, unsigned int* __restrict__ counter)
{
    if (blockIdx.x == 0) {
        if (threadIdx.x < NSLOT) slots[threadIdx.x * SLOT_STRIDE] = 0.f;
        if (threadIdx.x == NSLOT) *counter = 0u;
    }
    const int idx = blockIdx.x * 256 + threadIdx.x;   // 0 .. 262143
    const int s2  = idx >> 13;                        // slice pair 0..31
    const int r   = idx & (NROWS - 1);                // row
    const float4* src = x + (size_t)r * (DIM / 4) + s2 * 4;
    float4 a = src[0], b = src[1], c = src[2], d = src[3];
    uint2 lo, hi;
    lo.x = enc4(a.x, a.y, a.z, a.w);
    lo.y = enc4(b.x, b.y, b.z, b.w);
    hi.x = enc4(c.x, c.y, c.z, c.w);
    hi.y = enc4(d.x, d.y, d.z, d.w);
    xq_s[(size_t)(2 * s2) * NROWS + r]     = lo;
    xq_s[(size_t)(2 * s2 + 1) * NROWS + r] = hi;
}

__global__ __launch_bounds__(BT) void slice_gather_kernel(
    const uint2* __restrict__ xq_s,
    const int*   __restrict__ trip,
    __half*      __restrict__ zph)
{
    __shared__ uint2 sl[NROWS];                       // 64 KiB -> 2 blocks/CU
    const int s   = blockIdx.x & (NSLICE - 1);
    const int g   = blockIdx.x >> 6;
    const int tid = threadIdx.x;

    // stage slice s (contiguous 64 KB) with uint4 loads, coalesced
    const uint4* src4 = (const uint4*)(xq_s + (size_t)s * NROWS);
    uint4* sl4 = (uint4*)sl;
    #pragma unroll
    for (int q = 0; q < NROWS / 2 / BT; ++q)          // 4
        sl4[tid + q * BT] = src4[tid + q * BT];
    __syncthreads();

    __half* zrow = zph + (size_t)s * NTRIP;
    const int tbase = g * TRIP_PER_G + tid;

    // 2-stage pipeline: indices 2-deep, LDS data 1-deep.
    int ni = trip[3 * tbase + 0];
    int nj = trip[3 * tbase + 1];
    int nk = trip[3 * tbase + 2];
    int pi = trip[3 * (tbase + BT) + 0];
    int pj = trip[3 * (tbase + BT) + 1];
    int pk = trip[3 * (tbase + BT) + 2];
    uint2 da = sl[ni], db = sl[nj], dc = sl[nk];
    ni = pi; nj = pj; nk = pk;

    #pragma unroll
    for (int it = 0; it < NIT; ++it) {                // 8
        pi = 0; pj = 0; pk = 0;
        if (it + 2 < NIT) {
            const int tn = tbase + (it + 2) * BT;
            pi = trip[3 * tn + 0];
            pj = trip[3 * tn + 1];
            pk = trip[3 * tn + 2];
        }
        uint2 ea = {0, 0}, eb = {0, 0}, ec = {0, 0};
        if (it + 1 < NIT) { ea = sl[ni]; eb = sl[nj]; ec = sl[nk]; }
        // packed compute on previously-fetched registers
        floatx2 fa[4], fb[4], fc[4];
        decode8v(da, fa); decode8v(db, fb); decode8v(dc, fc);
        floatx2 acc = {0.f, 0.f};
        #pragma unroll
        for (int e = 0; e < 4; ++e) {
            floatx2 d = fa[e] - fb[e];
            floatx2 q = fa[e] - fc[e];
            acc = acc + d * d;                        // v_pk_fma_f32
            acc = acc - q * q;                        // v_pk_fma_f32 (neg)
        }
        zrow[tbase + it * BT] = __float2half(acc[0] + acc[1]);
        da = ea; db = eb; dc = ec;
        ni = pi; nj = pj; nk = pk;
    }
}

__global__ __launch_bounds__(256) void combine_kernel(
    const __half* __restrict__ zph,
    float*        __restrict__ slots,
    unsigned int* __restrict__ counter,
    float*        __restrict__ out)
{
    const int tid = threadIdx.x;
    float sp = 0.f;
    #pragma unroll
    for (int u = 0; u < 4; ++u) {
        const int t = blockIdx.x * 1024 + u * 256 + tid;
        float z = 0.f;
        #pragma unroll
        for (int s = 0; s < NSLICE; ++s)
            z += __half2float(zph[(size_t)s * NTRIP + t]);
        sp += softplus_stable(z);
    }
    #pragma unroll
    for (int m = 1; m < 64; m <<= 1)
        sp += __shfl_xor(sp, m, 64);

    __shared__ float ws[256 / 64];
    if ((tid & 63) == 0) ws[tid >> 6] = sp;
    __syncthreads();

    __shared__ bool amlast;
    if (tid == 0) {
        float bs = (ws[0] + ws[1]) + (ws[2] + ws[3]);
        atomicAdd(&slots[blockIdx.x * SLOT_STRIDE], bs);  // 1 add per slot
        unsigned int prev = __hip_atomic_fetch_add(
            counter, 1u, __ATOMIC_ACQ_REL, __HIP_MEMORY_SCOPE_AGENT);
        amlast = (prev == 63);
    }
    __syncthreads();

    if (amlast && tid < NSLOT) {
        float v = __hip_atomic_load(&slots[tid * SLOT_STRIDE],
                                    __ATOMIC_RELAXED, __HIP_MEMORY_SCOPE_AGENT);
        #pragma unroll
        for (int m = 1; m < NSLOT; m <<= 1)
            v += __shfl_xor(v, m, 64);
        if (tid == 0) out[0] = v / (float)NTRIP;
    }
}

// ====================== r7 PATH (proven 30.2 us) ======================

__global__ __launch_bounds__(256) void convert8_row_kernel(
    const float4* __restrict__ x, uint4* __restrict__ xq)
{
    const int idx = blockIdx.x * 256 + threadIdx.x;
    float4 a = x[(size_t)idx * 4 + 0];
    float4 b = x[(size_t)idx * 4 + 1];
    float4 c = x[(size_t)idx * 4 + 2];
    float4 d = x[(size_t)idx * 4 + 3];
    uint4 o;
    o.x = enc4(a.x, a.y, a.z, a.w);
    o.y = enc4(b.x, b.y, b.z, b.w);
    o.z = enc4(c.x, c.y, c.z, c.w);
    o.w = enc4(d.x, d.y, d.z, d.w);
    xq[idx] = o;
}

__global__ __launch_bounds__(256, 4) void gather8_kernel(
    const uint4* __restrict__ xq,
    const int*   __restrict__ trip,
    float*       __restrict__ partials)
{
    const int lane = threadIdx.x & 63;
    const int half = lane >> 5;
    const int l5   = lane & 31;
    const int wib  = threadIdx.x >> 6;
    const int t0   = (blockIdx.x * 4 + wib) * 8;

    const int4* tp = (const int4*)(trip + 3 * t0);
    int4 w0 = tp[0], w1 = tp[1], w2 = tp[2];
    int4 w3 = tp[3], w4 = tp[4], w5 = tp[5];
    const int id[24] = { w0.x, w0.y, w0.z, w0.w, w1.x, w1.y, w1.z, w1.w,
                         w2.x, w2.y, w2.z, w2.w, w3.x, w3.y, w3.z, w3.w,
                         w4.x, w4.y, w4.z, w4.w, w5.x, w5.y, w5.z, w5.w };

    uint4 r[4][3];
    #pragma unroll
    for (int g = 0; g < 4; ++g) {
        #pragma unroll
        for (int m = 0; m < 3; ++m) {
            const int row = half ? id[3 * (2 * g + 1) + m]
                                 : id[3 * (2 * g) + m];
            r[g][m] = xq[(size_t)row * 32 + l5];
        }
    }

    float z[4] = {0.f, 0.f, 0.f, 0.f};
    #pragma unroll
    for (int g = 0; g < 4; ++g) {
        float fa[16], fb[16], fc[16];
        decode16(r[g][0], fa);
        decode16(r[g][1], fb);
        decode16(r[g][2], fc);
        #pragma unroll
        for (int e = 0; e < 16; ++e) {
            float d = fa[e] - fb[e];
            float q = fa[e] - fc[e];
            z[g] += d * d - q * q;
        }
    }

    #pragma unroll
    for (int m = 1; m <= 16; m <<= 1) {
        #pragma unroll
        for (int g = 0; g < 4; ++g)
            z[g] += __shfl_xor(z[g], m, 64);
    }

    float sp = (softplus_stable(z[0]) + softplus_stable(z[1])) +
               (softplus_stable(z[2]) + softplus_stable(z[3]));
    sp += __shfl_xor(sp, 32, 64);

    __shared__ float wsum[4];
    if (lane == 0) wsum[wib] = sp;
    __syncthreads();
    if (threadIdx.x == 0)
        partials[blockIdx.x] = (wsum[0] + wsum[1]) + (wsum[2] + wsum[3]);
}

__global__ __launch_bounds__(1024) void reduce_kernel(
    const float* __restrict__ partials, float* __restrict__ out, int n)
{
    float s = 0.f;
    for (int idx = threadIdx.x; idx < n; idx += 1024)
        s += partials[idx];
    #pragma unroll
    for (int m = 1; m < 64; m <<= 1)
        s += __shfl_xor(s, m, 64);
    __shared__ float lds[1024 / 64];
    if ((threadIdx.x & 63) == 0) lds[threadIdx.x >> 6] = s;
    __syncthreads();
    if (threadIdx.x == 0) {
        float tot = 0.f;
        #pragma unroll
        for (int q = 0; q < 1024 / 64; ++q) tot += lds[q];
        out[0] = tot / (float)NTRIP;
    }
}

// ====================== fp32 fallback ======================
__global__ __launch_bounds__(256) void triplet_partial_f32(
    const float* __restrict__ x,
    const int*   __restrict__ trip,
    float*       __restrict__ partials)
{
    const int lane = threadIdx.x & 63;
    const int wib  = threadIdx.x >> 6;
    const int t    = blockIdx.x * 4 + wib;
    const int i = trip[3 * t + 0];
    const int j = trip[3 * t + 1];
    const int k = trip[3 * t + 2];
    const float4* pi = (const float4*)(x + (size_t)i * DIM) + lane * 2;
    const float4* pj = (const float4*)(x + (size_t)j * DIM) + lane * 2;
    const float4* pk = (const float4*)(x + (size_t)k * DIM) + lane * 2;
    float4 a0 = pi[0], a1 = pi[1];
    float4 b0 = pj[0], b1 = pj[1];
    float4 c0 = pk[0], c1 = pk[1];
    float z = 0.f;
    {
        float d;
        d = a0.x-b0.x; z += d*d; d = a0.y-b0.y; z += d*d;
        d = a0.z-b0.z; z += d*d; d = a0.w-b0.w; z += d*d;
        d = a1.x-b1.x; z += d*d; d = a1.y-b1.y; z += d*d;
        d = a1.z-b1.z; z += d*d; d = a1.w-b1.w; z += d*d;
        d = a0.x-c0.x; z -= d*d; d = a0.y-c0.y; z -= d*d;
        d = a0.z-c0.z; z -= d*d; d = a0.w-c0.w; z -= d*d;
        d = a1.x-c1.x; z -= d*d; d = a1.y-c1.y; z -= d*d;
        d = a1.z-c1.z; z -= d*d; d = a1.w-c1.w; z -= d*d;
    }
    #pragma unroll
    for (int m = 1; m < 64; m <<= 1) z += __shfl_xor(z, m, 64);
    __shared__ float wsum[4];
    if (lane == 0) wsum[wib] = softplus_stable(z);
    __syncthreads();
    if (threadIdx.x == 0)
        partials[blockIdx.x] = (wsum[0] + wsum[1]) + (wsum[2] + wsum[3]);
}

extern "C" void kernel_launch(void* const* d_in, const int* in_sizes, int n_in,
                              void* d_out, int out_size, void* d_ws, size_t ws_size,
                              hipStream_t stream) {
    const float* x    = (const float*)d_in[0];
    const int*   trip = (const int*)d_in[1];
    float*       out  = (float*)d_out;

    if (ws_size >= NEED_NEW) {
        uint2*        xq_s    = (uint2*)d_ws;
        __half*       zph     = (__half*)((char*)d_ws + XQS_BYTES);
        float*        slots   = (float*)((char*)d_ws + XQS_BYTES + ZP_BYTES);
        unsigned int* counter = (unsigned int*)((char*)d_ws + XQS_BYTES
                                 + ZP_BYTES + NSLOT * SLOT_STRIDE * 4);
        convert_slice_kernel<<<(NROWS * NSLICE / 2) / 256, 256, 0, stream>>>(
            (const float4*)x, xq_s, slots, counter);
        slice_gather_kernel<<<NSLICE * GGRP, BT, 0, stream>>>(xq_s, trip, zph);
        combine_kernel<<<NSLOT, 256, 0, stream>>>(zph, slots, counter, out);
    } else if (ws_size >= NEED_R7) {
        uint4* xq       = (uint4*)d_ws;
        float* partials = (float*)((char*)d_ws + XQ_BYTES);
        convert8_row_kernel<<<(NROWS * DIM / 16) / 256, 256, 0, stream>>>(
            (const float4*)x, xq);
        gather8_kernel<<<R7_NBLK, 256, 0, stream>>>(xq, trip, partials);
        reduce_kernel<<<1, 1024, 0, stream>>>(partials, out, R7_NBLK);
    } else {
        float* partials = (float*)d_ws;
        triplet_partial_f32<<<NTRIP / 4, 256, 0, stream>>>(x, trip, partials);
        reduce_kernel<<<1, 1024, 0, stream>>>(partials, out, NTRIP / 4);
    }
}

// Round 17
// 24.273 us; speedup vs baseline: 3.4110x; 3.4110x over previous
//
#include <hip/hip_runtime.h>
#include <hip/hip_fp16.h>

// TripletLoss: N=8192, D=512, T=65536
//   loss = mean_t softplus(||x_i - x_j||^2 - ||x_i - x_k||^2)
//
// Round 17: r14 scaffold (passed, 25.26us) with ONE change: combine_kernel's
// accumulation batches 32 independent 4-byte (__half2 = 2 triplets) loads
// into a register array before converting (MLP fix for the r15-profiled
// latency serialization at VGPR=12), + __launch_bounds__(256,4) for VGPR
// budget. Slot/counter scaffold byte-identical to r14 (proven no-crash).
//   A: fp32 -> fp8 e4m3 slice-major; zero 64 slots + counter (block 0).
//   B: 256 blocks (32 slices x 8 groups), stage 128 KiB slice in LDS,
//      2-stage pipelined loop, packed fma, zp[s][t] fp16 coalesced.
//   C: 64 blocks x 256 thr; 4 triplets/thread via 2 batches of 32
//      register-array loads; r14 slot reduce (1 add/slot, amlast).
// Fallback tiers: ws < 8.01 MB -> r7 path (proven 30.2); < 4.07 MB -> fp32.

typedef float floatx2 __attribute__((ext_vector_type(2)));

#define NTRIP  65536
#define DIM    512
#define NROWS  8192
#define NSLICE 32                  // 16 B of fp8 per row per slice
#define SLICE_U4 NROWS             // uint4 per slice
#define GGRP   8                   // triplet groups
#define TRIP_PER_G (NTRIP / GGRP)  // 8192
#define BT     1024                // kernel B block size (16 waves)
#define NIT    (TRIP_PER_G / BT)   // 8
#define NSLOT  64
#define SLOT_STRIDE 16             // floats; 64 B apart

#define XQS_BYTES ((size_t)NSLICE * SLICE_U4 * 16)      // 4 MiB
#define ZP_BYTES  ((size_t)NSLICE * NTRIP * 2)          // 4 MiB (fp16)
#define NEED_NEW  (XQS_BYTES + ZP_BYTES + NSLOT * SLOT_STRIDE * 4 + 64)
#define XQ_BYTES  ((size_t)NROWS * DIM)
#define R7_NBLK   2048
#define NEED_R7   (XQ_BYTES + (size_t)R7_NBLK * 4)

__device__ __forceinline__ float softplus_stable(float z) {
    return fmaxf(z, 0.f) + log1pf(expf(-fabsf(z)));
}

__device__ __forceinline__ unsigned int enc4(float a, float b, float c, float d) {
    unsigned int w = __builtin_amdgcn_cvt_pk_fp8_f32(a, b, 0, false);
    w = __builtin_amdgcn_cvt_pk_fp8_f32(c, d, w, true);
    return w;
}

__device__ __forceinline__ void decode16v(uint4 v, floatx2* f) {
    f[0] = __builtin_amdgcn_cvt_pk_f32_fp8(v.x, false);
    f[1] = __builtin_amdgcn_cvt_pk_f32_fp8(v.x, true);
    f[2] = __builtin_amdgcn_cvt_pk_f32_fp8(v.y, false);
    f[3] = __builtin_amdgcn_cvt_pk_f32_fp8(v.y, true);
    f[4] = __builtin_amdgcn_cvt_pk_f32_fp8(v.z, false);
    f[5] = __builtin_amdgcn_cvt_pk_f32_fp8(v.z, true);
    f[6] = __builtin_amdgcn_cvt_pk_f32_fp8(v.w, false);
    f[7] = __builtin_amdgcn_cvt_pk_f32_fp8(v.w, true);
}

__device__ __forceinline__ void decode4(unsigned int w, float* f) {
    floatx2 p0 = __builtin_amdgcn_cvt_pk_f32_fp8(w, false);
    floatx2 p1 = __builtin_amdgcn_cvt_pk_f32_fp8(w, true);
    f[0] = p0.x; f[1] = p0.y; f[2] = p1.x; f[3] = p1.y;
}

__device__ __forceinline__ void decode16(uint4 v, float* f) {
    decode4(v.x, f);     decode4(v.y, f + 4);
    decode4(v.z, f + 8); decode4(v.w, f + 12);
}

// ====================== NEW PATH (LDS slice) ======================

__global__ __launch_bounds__(256) void convert_slice_kernel(
    const float4* __restrict__ x, uint4* __restrict__ xq_s,
    float* __restrict__ slots, unsigned int* __restrict__ counter)
{
    if (blockIdx.x == 0) {
        if (threadIdx.x < NSLOT) slots[threadIdx.x * SLOT_STRIDE] = 0.f;
        if (threadIdx.x == NSLOT) *counter = 0u;
    }
    const int idx = blockIdx.x * 256 + threadIdx.x;   // 0 .. 262143
    const int s   = idx >> 13;                        // slice
    const int r   = idx & (NROWS - 1);                // row
    const float4* src = x + (size_t)r * (DIM / 4) + s * 4;
    float4 a = src[0], b = src[1], c = src[2], d = src[3];
    uint4 o;
    o.x = enc4(a.x, a.y, a.z, a.w);
    o.y = enc4(b.x, b.y, b.z, b.w);
    o.z = enc4(c.x, c.y, c.z, c.w);
    o.w = enc4(d.x, d.y, d.z, d.w);
    xq_s[idx] = o;                                    // = s*8192 + r
}

__global__ __launch_bounds__(BT) void slice_gather_kernel(
    const uint4* __restrict__ xq_s,
    const int*   __restrict__ trip,
    __half*      __restrict__ zph)
{
    __shared__ uint4 sl[SLICE_U4];                    // 128 KiB
    const int s   = blockIdx.x & (NSLICE - 1);
    const int g   = blockIdx.x >> 5;
    const int tid = threadIdx.x;

    // stage slice s (contiguous 128 KB), coalesced
    const uint4* src = xq_s + (size_t)s * SLICE_U4;
    #pragma unroll
    for (int q = 0; q < SLICE_U4 / BT; ++q)           // 8
        sl[tid + q * BT] = src[tid + q * BT];
    __syncthreads();

    __half* zrow = zph + (size_t)s * NTRIP;
    const int tbase = g * TRIP_PER_G + tid;

    // 2-stage pipeline: indices 2-deep, LDS data 1-deep.
    int ni = trip[3 * tbase + 0];
    int nj = trip[3 * tbase + 1];
    int nk = trip[3 * tbase + 2];
    int pi = trip[3 * (tbase + BT) + 0];
    int pj = trip[3 * (tbase + BT) + 1];
    int pk = trip[3 * (tbase + BT) + 2];
    uint4 da = sl[ni], db = sl[nj], dc = sl[nk];
    ni = pi; nj = pj; nk = pk;

    #pragma unroll
    for (int it = 0; it < NIT; ++it) {                // 8
        pi = 0; pj = 0; pk = 0;
        if (it + 2 < NIT) {
            const int tn = tbase + (it + 2) * BT;
            pi = trip[3 * tn + 0];
            pj = trip[3 * tn + 1];
            pk = trip[3 * tn + 2];
        }
        uint4 ea = {0, 0, 0, 0}, eb = {0, 0, 0, 0}, ec = {0, 0, 0, 0};
        if (it + 1 < NIT) { ea = sl[ni]; eb = sl[nj]; ec = sl[nk]; }
        // packed compute on previously-fetched registers
        floatx2 fa[8], fb[8], fc[8];
        decode16v(da, fa); decode16v(db, fb); decode16v(dc, fc);
        floatx2 acc = {0.f, 0.f};
        #pragma unroll
        for (int e = 0; e < 8; ++e) {
            floatx2 d = fa[e] - fb[e];
            floatx2 q = fa[e] - fc[e];
            acc = acc + d * d;                        // v_pk_fma_f32
            acc = acc - q * q;                        // v_pk_fma_f32 (neg)
        }
        zrow[tbase + it * BT] = __float2half(acc[0] + acc[1]);
        da = ea; db = eb; dc = ec;
        ni = pi; nj = pj; nk = pk;
    }
}

// C: 4 triplets/thread as 2 __half2-pair batches; each batch issues 32
// independent 4-byte loads into a register array BEFORE converting (MLP).
__global__ __launch_bounds__(256, 4) void combine_kernel(
    const __half* __restrict__ zph,
    float*        __restrict__ slots,
    unsigned int* __restrict__ counter,
    float*        __restrict__ out)
{
    const int tid  = threadIdx.x;
    const int base = (blockIdx.x * 256 + tid) * 4;    // 4 consecutive triplets

    float sp = 0.f;
    #pragma unroll
    for (int p = 0; p < 2; ++p) {
        unsigned int vv[NSLICE];
        #pragma unroll
        for (int s = 0; s < NSLICE; ++s)              // 32 independent loads
            vv[s] = *(const unsigned int*)(zph + (size_t)s * NTRIP
                                           + base + 2 * p);
        float z0 = 0.f, z1 = 0.f;
        #pragma unroll
        for (int s = 0; s < NSLICE; ++s) {
            float2 f = __half22float2(*(__half2*)&vv[s]);
            z0 += f.x; z1 += f.y;
        }
        sp += softplus_stable(z0) + softplus_stable(z1);
    }

    #pragma unroll
    for (int m = 1; m < 64; m <<= 1)
        sp += __shfl_xor(sp, m, 64);

    __shared__ float ws[256 / 64];
    if ((tid & 63) == 0) ws[tid >> 6] = sp;
    __syncthreads();

    __shared__ bool amlast;
    if (tid == 0) {
        float bs = (ws[0] + ws[1]) + (ws[2] + ws[3]);
        atomicAdd(&slots[blockIdx.x * SLOT_STRIDE], bs);  // 1 add per slot
        unsigned int prev = __hip_atomic_fetch_add(
            counter, 1u, __ATOMIC_ACQ_REL, __HIP_MEMORY_SCOPE_AGENT);
        amlast = (prev == 63);
    }
    __syncthreads();

    if (amlast && tid < NSLOT) {
        float v = __hip_atomic_load(&slots[tid * SLOT_STRIDE],
                                    __ATOMIC_RELAXED, __HIP_MEMORY_SCOPE_AGENT);
        #pragma unroll
        for (int m = 1; m < NSLOT; m <<= 1)
            v += __shfl_xor(v, m, 64);
        if (tid == 0) out[0] = v / (float)NTRIP;
    }
}

// ====================== r7 PATH (proven 30.2 us) ======================

__global__ __launch_bounds__(256) void convert8_row_kernel(
    const float4* __restrict__ x, uint4* __restrict__ xq)
{
    const int idx = blockIdx.x * 256 + threadIdx.x;
    float4 a = x[(size_t)idx * 4 + 0];
    float4 b = x[(size_t)idx * 4 + 1];
    float4 c = x[(size_t)idx * 4 + 2];
    float4 d = x[(size_t)idx * 4 + 3];
    uint4 o;
    o.x = enc4(a.x, a.y, a.z, a.w);
    o.y = enc4(b.x, b.y, b.z, b.w);
    o.z = enc4(c.x, c.y, c.z, c.w);
    o.w = enc4(d.x, d.y, d.z, d.w);
    xq[idx] = o;
}

__global__ __launch_bounds__(256, 4) void gather8_kernel(
    const uint4* __restrict__ xq,
    const int*   __restrict__ trip,
    float*       __restrict__ partials)
{
    const int lane = threadIdx.x & 63;
    const int half = lane >> 5;
    const int l5   = lane & 31;
    const int wib  = threadIdx.x >> 6;
    const int t0   = (blockIdx.x * 4 + wib) * 8;

    const int4* tp = (const int4*)(trip + 3 * t0);
    int4 w0 = tp[0], w1 = tp[1], w2 = tp[2];
    int4 w3 = tp[3], w4 = tp[4], w5 = tp[5];
    const int id[24] = { w0.x, w0.y, w0.z, w0.w, w1.x, w1.y, w1.z, w1.w,
                         w2.x, w2.y, w2.z, w2.w, w3.x, w3.y, w3.z, w3.w,
                         w4.x, w4.y, w4.z, w4.w, w5.x, w5.y, w5.z, w5.w };

    uint4 r[4][3];
    #pragma unroll
    for (int g = 0; g < 4; ++g) {
        #pragma unroll
        for (int m = 0; m < 3; ++m) {
            const int row = half ? id[3 * (2 * g + 1) + m]
                                 : id[3 * (2 * g) + m];
            r[g][m] = xq[(size_t)row * 32 + l5];
        }
    }

    float z[4] = {0.f, 0.f, 0.f, 0.f};
    #pragma unroll
    for (int g = 0; g < 4; ++g) {
        float fa[16], fb[16], fc[16];
        decode16(r[g][0], fa);
        decode16(r[g][1], fb);
        decode16(r[g][2], fc);
        #pragma unroll
        for (int e = 0; e < 16; ++e) {
            float d = fa[e] - fb[e];
            float q = fa[e] - fc[e];
            z[g] += d * d - q * q;
        }
    }

    #pragma unroll
    for (int m = 1; m <= 16; m <<= 1) {
        #pragma unroll
        for (int g = 0; g < 4; ++g)
            z[g] += __shfl_xor(z[g], m, 64);
    }

    float sp = (softplus_stable(z[0]) + softplus_stable(z[1])) +
               (softplus_stable(z[2]) + softplus_stable(z[3]));
    sp += __shfl_xor(sp, 32, 64);

    __shared__ float wsum[4];
    if (lane == 0) wsum[wib] = sp;
    __syncthreads();
    if (threadIdx.x == 0)
        partials[blockIdx.x] = (wsum[0] + wsum[1]) + (wsum[2] + wsum[3]);
}

__global__ __launch_bounds__(1024) void reduce_kernel(
    const float* __restrict__ partials, float* __restrict__ out, int n)
{
    float s = 0.f;
    for (int idx = threadIdx.x; idx < n; idx += 1024)
        s += partials[idx];
    #pragma unroll
    for (int m = 1; m < 64; m <<= 1)
        s += __shfl_xor(s, m, 64);
    __shared__ float lds[1024 / 64];
    if ((threadIdx.x & 63) == 0) lds[threadIdx.x >> 6] = s;
    __syncthreads();
    if (threadIdx.x == 0) {
        float tot = 0.f;
        #pragma unroll
        for (int q = 0; q < 1024 / 64; ++q) tot += lds[q];
        out[0] = tot / (float)NTRIP;
    }
}

// ====================== fp32 fallback ======================
__global__ __launch_bounds__(256) void triplet_partial_f32(
    const float* __restrict__ x,
    const int*   __restrict__ trip,
    float*       __restrict__ partials)
{
    const int lane = threadIdx.x & 63;
    const int wib  = threadIdx.x >> 6;
    const int t    = blockIdx.x * 4 + wib;
    const int i = trip[3 * t + 0];
    const int j = trip[3 * t + 1];
    const int k = trip[3 * t + 2];
    const float4* pi = (const float4*)(x + (size_t)i * DIM) + lane * 2;
    const float4* pj = (const float4*)(x + (size_t)j * DIM) + lane * 2;
    const float4* pk = (const float4*)(x + (size_t)k * DIM) + lane * 2;
    float4 a0 = pi[0], a1 = pi[1];
    float4 b0 = pj[0], b1 = pj[1];
    float4 c0 = pk[0], c1 = pk[1];
    float z = 0.f;
    {
        float d;
        d = a0.x-b0.x; z += d*d; d = a0.y-b0.y; z += d*d;
        d = a0.z-b0.z; z += d*d; d = a0.w-b0.w; z += d*d;
        d = a1.x-b1.x; z += d*d; d = a1.y-b1.y; z += d*d;
        d = a1.z-b1.z; z += d*d; d = a1.w-b1.w; z += d*d;
        d = a0.x-c0.x; z -= d*d; d = a0.y-c0.y; z -= d*d;
        d = a0.z-c0.z; z -= d*d; d = a0.w-c0.w; z -= d*d;
        d = a1.x-c1.x; z -= d*d; d = a1.y-c1.y; z -= d*d;
        d = a1.z-c1.z; z -= d*d; d = a1.w-c1.w; z -= d*d;
    }
    #pragma unroll
    for (int m = 1; m < 64; m <<= 1) z += __shfl_xor(z, m, 64);
    __shared__ float wsum[4];
    if (lane == 0) wsum[wib] = softplus_stable(z);
    __syncthreads();
    if (threadIdx.x == 0)
        partials[blockIdx.x] = (wsum[0] + wsum[1]) + (wsum[2] + wsum[3]);
}

extern "C" void kernel_launch(void* const* d_in, const int* in_sizes, int n_in,
                              void* d_out, int out_size, void* d_ws, size_t ws_size,
                              hipStream_t stream) {
    const float* x    = (const float*)d_in[0];
    const int*   trip = (const int*)d_in[1];
    float*       out  = (float*)d_out;

    if (ws_size >= NEED_NEW) {
        uint4*        xq_s    = (uint4*)d_ws;
        __half*       zph     = (__half*)((char*)d_ws + XQS_BYTES);
        float*        slots   = (float*)((char*)d_ws + XQS_BYTES + ZP_BYTES);
        unsigned int* counter = (unsigned int*)((char*)d_ws + XQS_BYTES
                                 + ZP_BYTES + NSLOT * SLOT_STRIDE * 4);
        convert_slice_kernel<<<(NROWS * NSLICE) / 256, 256, 0, stream>>>(
            (const float4*)x, xq_s, slots, counter);
        slice_gather_kernel<<<NSLICE * GGRP, BT, 0, stream>>>(xq_s, trip, zph);
        combine_kernel<<<NSLOT, 256, 0, stream>>>(zph, slots, counter, out);
    } else if (ws_size >= NEED_R7) {
        uint4* xq       = (uint4*)d_ws;
        float* partials = (float*)((char*)d_ws + XQ_BYTES);
        convert8_row_kernel<<<(NROWS * DIM / 16) / 256, 256, 0, stream>>>(
            (const float4*)x, xq);
        gather8_kernel<<<R7_NBLK, 256, 0, stream>>>(xq, trip, partials);
        reduce_kernel<<<1, 1024, 0, stream>>>(partials, out, R7_NBLK);
    } else {
        float* partials = (float*)d_ws;
        triplet_partial_f32<<<NTRIP / 4, 256, 0, stream>>>(x, trip, partials);
        reduce_kernel<<<1, 1024, 0, stream>>>(partials, out, NTRIP / 4);
    }
}